// Round 15
// baseline (184.953 us; speedup 1.0000x reference)
//
#include <hip/hip_runtime.h>
#include <hip/hip_fp16.h>

#define NN 50000
#define NM 50000
#define F  128
#define NGRP 196      // ceil(50000/256) coarse groups of 256 dest ids
#define CHSZ 8192     // edges per sort chunk
#define PSZ  10240    // merge pairs buffer (mean 8192, +22 sigma)
typedef unsigned short ushort_t;
typedef _Float16 f16;
typedef f16 f16x8 __attribute__((ext_vector_type(8)));
typedef float f32x4 __attribute__((ext_vector_type(4)));

union HF4 { float4 f4; __half2 h2[4]; };
union PK4 { uint2 u2; f16 h[4]; };

// ---------------- block-scan helpers ---------------------------------------------
__device__ __forceinline__ int wscan64(int v, int lane) {
    int x = v;
#pragma unroll
    for (int s = 1; s < 64; s <<= 1) {
        int u = __shfl_up(x, s, 64);
        if (lane >= s) x += u;
    }
    return x;   // inclusive
}

__device__ __forceinline__ int bscan256(int v, int* s5, int* tot) {
    int t = threadIdx.x, lane = t & 63, wid = t >> 6;
    int incl = wscan64(v, lane);
    if (lane == 63) s5[wid] = incl;
    __syncthreads();
    if (t == 0) {
        int a = 0;
#pragma unroll
        for (int j = 0; j < 4; ++j) { int x = s5[j]; s5[j] = a; a += x; }
        s5[4] = a;
    }
    __syncthreads();
    int ex = incl - v + s5[wid];
    *tot = s5[4];
    __syncthreads();
    return ex;
}

// ---------------- W prep: Wt[col][k] fp16 ----------------------------------------
__global__ __launch_bounds__(256) void wprep_k(const float* __restrict__ W,
                                               f16* __restrict__ Wt) {
    int i = blockIdx.x * 256 + threadIdx.x;   // 16384
    int k = i >> 7, c = i & 127;
    Wt[c * 128 + k] = (f16)W[i];
}

// ---------------- fat kernel: chunksort blocks [0,nsort) + MFMA-gemm blocks ------
struct GemmSmem { f16 sXh[64 * 128]; };                                            // 16KB
struct SortSmem { int hist[NGRP]; int cursor[NGRP]; int pairs[CHSZ]; int s5[5]; }; // 33.6KB
union alignas(16) FatSmem { GemmSmem g; SortSmem s; };

__global__ __launch_bounds__(256) void fat_k(const float* __restrict__ X,
                                             const f16* __restrict__ Wt,
                                             f16* __restrict__ xh,      // row-major [NN][128] fp16
                                             const int* __restrict__ nodes,
                                             const int* __restrict__ hedges,
                                             int* __restrict__ gchunk0, int* __restrict__ gchunk1,
                                             int* __restrict__ ghist, int* __restrict__ gstart,
                                             int E, int NCH, int nsort) {
    __shared__ FatSmem u;
    int t = threadIdx.x;

    if ((int)blockIdx.x < nsort) {
        // ---------------- chunksort by coarse group (key>>8) ----------------
        int dir = blockIdx.x / NCH;
        int c   = blockIdx.x % NCH;
        const int* key = dir ? nodes  : hedges;
        const int* pay = dir ? hedges : nodes;
        int* gchunk    = dir ? gchunk1 : gchunk0;
        int e0 = c * CHSZ, e1 = min(E, e0 + CHSZ);

        if (t < NGRP) u.s.hist[t] = 0;
        __syncthreads();
        for (int e = e0 + t; e < e1; e += 256) atomicAdd(&u.s.hist[key[e] >> 8], 1);
        __syncthreads();

        {
            int v = (t < NGRP) ? u.s.hist[t] : 0;
            int tot;
            int ex = bscan256(v, u.s.s5, &tot);
            if (t < NGRP) u.s.cursor[t] = ex;
        }
        __syncthreads();

        if (t < NGRP) {
            size_t idx = ((size_t)dir * NGRP + t) * NCH + c;
            ghist[idx]  = u.s.hist[t];
            gstart[idx] = u.s.cursor[t];
        }
        __syncthreads();

        for (int e = e0 + t; e < e1; e += 256) {
            int k = key[e];
            int pos = atomicAdd(&u.s.cursor[k >> 8], 1);
            u.s.pairs[pos] = ((k & 255) << 16) | pay[e];
        }
        __syncthreads();

        int n = e1 - e0;
        for (int i = t; i < n; i += 256) gchunk[(size_t)c * CHSZ + i] = u.s.pairs[i];
    } else {
        // ---------------- MFMA gemm: xh[64 rows] = X @ W -> fp16 ----------------
        int gb = blockIdx.x - nsort;
        int row0 = gb * 64;

        const float4* X4 = (const float4*)X;
        for (int i = t; i < 64 * 32; i += 256) {
            int r = i >> 5, cq = i & 31;
            int gr = row0 + r;
            float4 xv = (gr < NN) ? X4[(size_t)gr * 32 + cq]
                                  : make_float4(0.f, 0.f, 0.f, 0.f);
            PK4 pk;
            pk.h[0] = (f16)xv.x; pk.h[1] = (f16)xv.y;
            pk.h[2] = (f16)xv.z; pk.h[3] = (f16)xv.w;
            int byte = (r * 256 + cq * 8) ^ ((r & 7) << 4);
            *(uint2*)((char*)u.g.sXh + byte) = pk.u2;
        }
        __syncthreads();

        int l = t & 63, w = t >> 6;
        int lr = l & 15, lk = l >> 4;
        f32x4 acc[8];
#pragma unroll
        for (int c = 0; c < 8; ++c) acc[c] = (f32x4){0.f, 0.f, 0.f, 0.f};

#pragma unroll
        for (int ks = 0; ks < 4; ++ks) {
            int rloc = w * 16 + lr;
            int abyte = (rloc * 256 + ks * 64 + lk * 16) ^ ((rloc & 7) << 4);
            f16x8 afrag = *(const f16x8*)((const char*)u.g.sXh + abyte);
#pragma unroll
            for (int c = 0; c < 8; ++c) {
                f16x8 bfrag = *(const f16x8*)(Wt + (c * 16 + lr) * 128 + ks * 32 + lk * 8);
                acc[c] = __builtin_amdgcn_mfma_f32_16x16x32_f16(afrag, bfrag, acc[c], 0, 0, 0);
            }
        }

#pragma unroll
        for (int c = 0; c < 8; ++c) {
            int col = c * 16 + lr;
#pragma unroll
            for (int j = 0; j < 4; ++j) {
                int row = row0 + w * 16 + lk * 4 + j;
                if (row < NN) xh[(size_t)row * 128 + col] = (f16)acc[c][j];
            }
        }
    }
}

// ---------------- 2a: per-row sum of ghist (1 wave per row) ----------------------
__global__ __launch_bounds__(256) void rowsum_k(const int* __restrict__ ghist,
                                                int* __restrict__ bsum, int NCH) {
    int row = blockIdx.x * 4 + (threadIdx.x >> 6);
    int l = threadIdx.x & 63;
    if (row >= 2 * NGRP) return;
    const int* r = ghist + (size_t)row * NCH;
    int s = 0;
    for (int c = l; c < NCH; c += 64) s += r[c];
#pragma unroll
    for (int k = 32; k >= 1; k >>= 1) s += __shfl_xor(s, k, 64);
    if (l == 0) bsum[row] = s;
}

// ---------------- 2b: scan group sums -> global group starts ---------------------
__global__ __launch_bounds__(256) void bucketbase_k(const int* __restrict__ bsum,
                                                    int* __restrict__ bstart,
                                                    int* __restrict__ off0, int* __restrict__ off1,
                                                    int E) {
    __shared__ int s5[5];
    int dir = blockIdx.x;
    int t = threadIdx.x;
    int v = (t < NGRP) ? bsum[dir * NGRP + t] : 0;
    int tot;
    int ex = bscan256(v, s5, &tot);
    if (t < NGRP) bstart[dir * NGRP + t] = ex;
    if (t == 0) (dir ? off1 : off0)[50000] = E;
}

// ---------------- 3: per-group merge + 256-way fine sort + scatter ---------------
__global__ __launch_bounds__(256) void merge_scatter_k(const int* __restrict__ gchunk0, const int* __restrict__ gchunk1,
                                                       const int* __restrict__ ghist, const int* __restrict__ gstart,
                                                       const int* __restrict__ bstart,
                                                       ushort_t* __restrict__ adj0, ushort_t* __restrict__ adj1,
                                                       int* __restrict__ off0, int* __restrict__ off1,
                                                       int NCH) {
    __shared__ int ssrc[256];
    __shared__ int sdst[257];
    __shared__ int s5[5];
    __shared__ int pairsS[PSZ];
    __shared__ int fcur[256];

    int dir = blockIdx.x / NGRP;
    int g   = blockIdx.x % NGRP;
    int t   = threadIdx.x;
    const int* gchunk   = dir ? gchunk1 : gchunk0;
    ushort_t* adj       = dir ? adj1 : adj0;
    int* offD           = dir ? off1 : off0;

    int len = 0, src = 0;
    if (t < NCH) {
        size_t idx = ((size_t)dir * NGRP + g) * NCH + t;
        len = ghist[idx];
        src = gstart[idx];
    }
    ssrc[t] = src;
    int tot;
    int ex = bscan256(len, s5, &tot);
    sdst[t] = ex;
    if (t == 0) sdst[256] = 0x7FFFFFFF;
    fcur[t] = 0;
    __syncthreads();
    int T = min(tot, PSZ);

    int per = (T + 255) >> 8;
    int i0 = t * per, i1 = min(T, i0 + per);
    if (i0 < i1) {
        int lo = 0, hi = 255;
        while (lo < hi) {
            int mid = (lo + hi + 1) >> 1;
            if (sdst[mid] <= i0) lo = mid; else hi = mid - 1;
        }
        int c = lo;
        for (int i = i0; i < i1; ++i) {
            while (c < 255 && sdst[c + 1] <= i) ++c;
            int p = gchunk[(size_t)c * CHSZ + ssrc[c] + (i - sdst[c])];
            pairsS[i] = p;
            atomicAdd(&fcur[(p >> 16) & 255], 1);
        }
    }
    __syncthreads();

    int cnt = fcur[t];
    __syncthreads();
    int ftot;
    int fex = bscan256(cnt, s5, &ftot);
    int bst = bstart[dir * NGRP + g];
    fcur[t] = fex;
    int d = g * 256 + t;
    if (d < 50000) offD[d] = bst + fex;
    __syncthreads();

    for (int i = t; i < T; i += 256) {
        int p = pairsS[i];
        int slot = atomicAdd(&fcur[(p >> 16) & 255], 1);
        adj[(size_t)bst + slot] = (ushort_t)(p & 0xFFFF);
    }
}

// ---------------- gather-sum core: 1 wave/segment, ushort4 idx, fp16 accum -------
__device__ __forceinline__ void gather_sum(const char* __restrict__ tb,
                                           const ushort_t* __restrict__ adj,
                                           int p0, int p1, int rg, unsigned int cb,
                                           float v[8]) {
    __half2 z = __floats2half2_rn(0.f, 0.f);
    __half2 a0 = z, a1 = z, a2 = z, a3 = z;

    // peel to 4-entry (8B) alignment: group rg handles entry p0+rg
    int pre = min((4 - (p0 & 3)) & 3, p1 - p0);
    if (rg < pre) {
        unsigned int o = ((unsigned int)adj[p0 + rg] << 8) + cb;
        HF4 u; u.f4 = *(const float4*)(tb + o);
        a0 = __hadd2(a0, u.h2[0]); a1 = __hadd2(a1, u.h2[1]);
        a2 = __hadd2(a2, u.h2[2]); a3 = __hadd2(a3, u.h2[3]);
    }
    int i = p0 + pre;

    // 32-entry main loop: 2 ushort4 index loads, 8 row loads in flight
    for (; i + 32 <= p1; i += 32) {
        ushort4 q0 = *(const ushort4*)(adj + i + rg * 4);
        ushort4 q1 = *(const ushort4*)(adj + i + 16 + rg * 4);
        HF4 u0, u1, u2, u3, u4, u5, u6, u7;
        u0.f4 = *(const float4*)(tb + (((unsigned int)q0.x << 8) + cb));
        u1.f4 = *(const float4*)(tb + (((unsigned int)q0.y << 8) + cb));
        u2.f4 = *(const float4*)(tb + (((unsigned int)q0.z << 8) + cb));
        u3.f4 = *(const float4*)(tb + (((unsigned int)q0.w << 8) + cb));
        u4.f4 = *(const float4*)(tb + (((unsigned int)q1.x << 8) + cb));
        u5.f4 = *(const float4*)(tb + (((unsigned int)q1.y << 8) + cb));
        u6.f4 = *(const float4*)(tb + (((unsigned int)q1.z << 8) + cb));
        u7.f4 = *(const float4*)(tb + (((unsigned int)q1.w << 8) + cb));
#pragma unroll
        for (int k = 0; k < 4; ++k) {
            __half2 s0 = __hadd2(u0.h2[k], u1.h2[k]);
            __half2 s1 = __hadd2(u2.h2[k], u3.h2[k]);
            __half2 s2 = __hadd2(u4.h2[k], u5.h2[k]);
            __half2 s3 = __hadd2(u6.h2[k], u7.h2[k]);
            __half2 s = __hadd2(__hadd2(s0, s1), __hadd2(s2, s3));
            if (k == 0) a0 = __hadd2(a0, s);
            else if (k == 1) a1 = __hadd2(a1, s);
            else if (k == 2) a2 = __hadd2(a2, s);
            else a3 = __hadd2(a3, s);
        }
    }
    // 16-entry step
    if (i + 16 <= p1) {
        ushort4 q0 = *(const ushort4*)(adj + i + rg * 4);
        HF4 u0, u1, u2, u3;
        u0.f4 = *(const float4*)(tb + (((unsigned int)q0.x << 8) + cb));
        u1.f4 = *(const float4*)(tb + (((unsigned int)q0.y << 8) + cb));
        u2.f4 = *(const float4*)(tb + (((unsigned int)q0.z << 8) + cb));
        u3.f4 = *(const float4*)(tb + (((unsigned int)q0.w << 8) + cb));
#pragma unroll
        for (int k = 0; k < 4; ++k) {
            __half2 s01 = __hadd2(u0.h2[k], u1.h2[k]);
            __half2 s23 = __hadd2(u2.h2[k], u3.h2[k]);
            __half2 s = __hadd2(s01, s23);
            if (k == 0) a0 = __hadd2(a0, s);
            else if (k == 1) a1 = __hadd2(a1, s);
            else if (k == 2) a2 = __hadd2(a2, s);
            else a3 = __hadd2(a3, s);
        }
        i += 16;
    }
    // scalar tail (<16 entries): group rg handles entry i+rg per 4-step
    for (; i < p1; i += 4) {
        int r = i + rg;
        if (r < p1) {
            unsigned int o = ((unsigned int)adj[r] << 8) + cb;
            HF4 u; u.f4 = *(const float4*)(tb + o);
            a0 = __hadd2(a0, u.h2[0]); a1 = __hadd2(a1, u.h2[1]);
            a2 = __hadd2(a2, u.h2[2]); a3 = __hadd2(a3, u.h2[3]);
        }
    }

    float2 f0 = __half22float2(a0), f1 = __half22float2(a1);
    float2 f2 = __half22float2(a2), f3 = __half22float2(a3);
    v[0] = f0.x; v[1] = f0.y; v[2] = f1.x; v[3] = f1.y;
    v[4] = f2.x; v[5] = f2.y; v[6] = f3.x; v[7] = f3.y;
#pragma unroll
    for (int k = 0; k < 8; ++k) {
        v[k] += __shfl_xor(v[k], 16, 64);
        v[k] += __shfl_xor(v[k], 32, 64);
    }
}

// ---------------- pass A: m[h] = B_inv[h] * sum_{v in h} x[v] --------------------
__global__ __launch_bounds__(256) void agg_a_k(const char* __restrict__ xb,
                                               const ushort_t* __restrict__ adj,
                                               const int* __restrict__ off,
                                               float4* __restrict__ m4) {
    int t = threadIdx.x;
    int seg = blockIdx.x * 4 + (t >> 6);
    int l = t & 63;
    int rg = l >> 4;
    unsigned int cb = (unsigned int)(l & 15) << 4;
    int p0 = off[seg], p1 = off[seg + 1];
    float v[8];
    gather_sum(xb, adj, p0, p1, rg, cb, v);
    if (l < 16) {
        float inv = (p1 > p0) ? 1.0f / (float)(p1 - p0) : 0.0f;
        HF4 w;
#pragma unroll
        for (int k = 0; k < 4; ++k)
            w.h2[k] = __floats2half2_rn(v[2 * k] * inv, v[2 * k + 1] * inv);
        m4[(size_t)seg * 16 + (l & 15)] = w.f4;
    }
}

// ---------------- pass B: out[v] = softmax(D_inv[v]*sum m[h] + b) (fused) --------
__global__ __launch_bounds__(256) void agg_b_k(const char* __restrict__ mb,
                                               const ushort_t* __restrict__ adj,
                                               const int* __restrict__ off,
                                               const float* __restrict__ bias,
                                               float4* __restrict__ out4) {
    int t = threadIdx.x;
    int seg = blockIdx.x * 4 + (t >> 6);
    int l = t & 63;
    int rg = l >> 4;
    int cc = l & 15;
    unsigned int cb = (unsigned int)cc << 4;
    int p0 = off[seg], p1 = off[seg + 1];
    float v[8];
    gather_sum(mb, adj, p0, p1, rg, cb, v);

    float inv = (p1 > p0) ? 1.0f / (float)(p1 - p0) : 0.0f;
    const float4* b4 = (const float4*)bias;
    float4 bb0 = b4[cc * 2], bb1 = b4[cc * 2 + 1];
    float lg[8];
    lg[0] = v[0] * inv + bb0.x; lg[1] = v[1] * inv + bb0.y;
    lg[2] = v[2] * inv + bb0.z; lg[3] = v[3] * inv + bb0.w;
    lg[4] = v[4] * inv + bb1.x; lg[5] = v[5] * inv + bb1.y;
    lg[6] = v[6] * inv + bb1.z; lg[7] = v[7] * inv + bb1.w;

    float mx = lg[0];
#pragma unroll
    for (int k = 1; k < 8; ++k) mx = fmaxf(mx, lg[k]);
#pragma unroll
    for (int s = 1; s < 16; s <<= 1) mx = fmaxf(mx, __shfl_xor(mx, s, 16));
    float e[8], sm = 0.f;
#pragma unroll
    for (int k = 0; k < 8; ++k) { e[k] = __expf(lg[k] - mx); sm += e[k]; }
#pragma unroll
    for (int s = 1; s < 16; s <<= 1) sm += __shfl_xor(sm, s, 16);
    float r = 1.0f / sm;
    if (l < 16) {
        out4[(size_t)seg * 32 + cc * 2]     = make_float4(e[0] * r, e[1] * r, e[2] * r, e[3] * r);
        out4[(size_t)seg * 32 + cc * 2 + 1] = make_float4(e[4] * r, e[5] * r, e[6] * r, e[7] * r);
    }
}

// ---------------- launcher -------------------------------------------------------
extern "C" void kernel_launch(void* const* d_in, const int* in_sizes, int n_in,
                              void* d_out, int out_size, void* d_ws, size_t ws_size,
                              hipStream_t stream) {
    const float* X  = (const float*)d_in[0];
    const int*   ei = (const int*)d_in[1];
    const float* W  = (const float*)d_in[2];
    const float* b  = (const float*)d_in[3];

    int E = in_sizes[1] / 2;
    const int* nodes  = ei;
    const int* hedges = ei + E;
    int NCH = (E + CHSZ - 1) / CHSZ;       // 196 for E=1.6M (must be <= 256)
    int nsort = 2 * NCH;
    int gemmb = (NN + 63) / 64;            // 782 MFMA-gemm blocks

    // workspace layout (~50 MB)
    char* p = (char*)d_ws;
    f16* xh = (f16*)p;                    p += (size_t)NN * F * 2;            // 12.8MB
    f16* mh = (f16*)p;                    p += (size_t)NM * F * 2;            // 12.8MB
    ushort_t* adj0 = (ushort_t*)p;        p += (size_t)E * 2;                 // 3.2MB
    ushort_t* adj1 = (ushort_t*)p;        p += (size_t)E * 2;                 // 3.2MB
    int* ghist  = (int*)p;                p += (size_t)2 * NGRP * NCH * 4;    // 300KB
    int* gstart = (int*)p;                p += (size_t)2 * NGRP * NCH * 4;    // 300KB
    int* bstart = (int*)p;                p += (size_t)2 * NGRP * 4;
    int* bsum   = (int*)p;                p += (size_t)2 * NGRP * 4;
    int* off0   = (int*)p;                p += (size_t)(NN + 1) * 4;
    int* off1   = (int*)p;                p += (size_t)(NN + 1) * 4;
    f16* Wt     = (f16*)p;                p += (size_t)128 * 128 * 2;         // 32KB
    p = (char*)(((uintptr_t)p + 15) & ~(uintptr_t)15);
    int* gchunk0 = (int*)p;                                                   // NCH*CHSZ ints
    int* gchunk1 = gchunk0 + (size_t)NCH * CHSZ;

    wprep_k<<<64, 256, 0, stream>>>(W, Wt);
    fat_k<<<nsort + gemmb, 256, 0, stream>>>(X, Wt, xh, nodes, hedges,
                                             gchunk0, gchunk1, ghist, gstart, E, NCH, nsort);
    rowsum_k<<<(2 * NGRP + 3) / 4, 256, 0, stream>>>(ghist, bsum, NCH);
    bucketbase_k<<<2, 256, 0, stream>>>(bsum, bstart, off0, off1, E);
    merge_scatter_k<<<2 * NGRP, 256, 0, stream>>>(gchunk0, gchunk1, ghist, gstart, bstart,
                                                  adj0, adj1, off0, off1, NCH);
    agg_a_k<<<NM / 4, 256, 0, stream>>>((const char*)xh, adj0, off0, (float4*)mh);
    agg_b_k<<<NN / 4, 256, 0, stream>>>((const char*)mh, adj1, off1, b, (float4*)d_out);
}

// Round 16
// 178.544 us; speedup vs baseline: 1.0359x; 1.0359x over previous
//
#include <hip/hip_runtime.h>
#include <hip/hip_fp16.h>

#define NN 50000
#define NM 50000
#define F  128
#define NGRP 196      // ceil(50000/256) coarse groups of 256 dest ids
#define CHSZ 8192     // edges per sort chunk
#define PSZ  10240    // merge pairs buffer (mean 8192, +22 sigma)
typedef unsigned short ushort_t;
typedef _Float16 f16;
typedef f16 f16x8 __attribute__((ext_vector_type(8)));
typedef float f32x4 __attribute__((ext_vector_type(4)));

union HF4 { float4 f4; __half2 h2[4]; };
union PK4 { uint2 u2; f16 h[4]; };

// ---------------- block-scan helpers ---------------------------------------------
__device__ __forceinline__ int wscan64(int v, int lane) {
    int x = v;
#pragma unroll
    for (int s = 1; s < 64; s <<= 1) {
        int u = __shfl_up(x, s, 64);
        if (lane >= s) x += u;
    }
    return x;   // inclusive
}

__device__ __forceinline__ int bscan256(int v, int* s5, int* tot) {
    int t = threadIdx.x, lane = t & 63, wid = t >> 6;
    int incl = wscan64(v, lane);
    if (lane == 63) s5[wid] = incl;
    __syncthreads();
    if (t == 0) {
        int a = 0;
#pragma unroll
        for (int j = 0; j < 4; ++j) { int x = s5[j]; s5[j] = a; a += x; }
        s5[4] = a;
    }
    __syncthreads();
    int ex = incl - v + s5[wid];
    *tot = s5[4];
    __syncthreads();
    return ex;
}

// ---------------- W prep: Wt[col][k] fp16 ----------------------------------------
__global__ __launch_bounds__(256) void wprep_k(const float* __restrict__ W,
                                               f16* __restrict__ Wt) {
    int i = blockIdx.x * 256 + threadIdx.x;   // 16384
    int k = i >> 7, c = i & 127;
    Wt[c * 128 + k] = (f16)W[i];
}

// ---------------- fat kernel: chunksort blocks [0,nsort) + MFMA-gemm blocks ------
// gemm blocks now cover 128 rows each -> 391 blocks; 392+391=783 <= 1024 slots
// (4 blocks/CU at 33.6KB LDS) -> single dispatch round.
struct GemmSmem { f16 sXh[128 * 128]; };                                           // 32KB
struct SortSmem { int hist[NGRP]; int cursor[NGRP]; int pairs[CHSZ]; int s5[5]; }; // 33.6KB
union alignas(16) FatSmem { GemmSmem g; SortSmem s; };

__global__ __launch_bounds__(256) void fat_k(const float* __restrict__ X,
                                             const f16* __restrict__ Wt,
                                             f16* __restrict__ xh,      // row-major [NN][128] fp16
                                             const int* __restrict__ nodes,
                                             const int* __restrict__ hedges,
                                             int* __restrict__ gchunk0, int* __restrict__ gchunk1,
                                             int* __restrict__ ghist, int* __restrict__ gstart,
                                             int E, int NCH, int nsort) {
    __shared__ FatSmem u;
    int t = threadIdx.x;

    if ((int)blockIdx.x < nsort) {
        // ---------------- chunksort by coarse group (key>>8) ----------------
        int dir = blockIdx.x / NCH;
        int c   = blockIdx.x % NCH;
        const int* key = dir ? nodes  : hedges;
        const int* pay = dir ? hedges : nodes;
        int* gchunk    = dir ? gchunk1 : gchunk0;
        int e0 = c * CHSZ, e1 = min(E, e0 + CHSZ);

        if (t < NGRP) u.s.hist[t] = 0;
        __syncthreads();
        for (int e = e0 + t; e < e1; e += 256) atomicAdd(&u.s.hist[key[e] >> 8], 1);
        __syncthreads();

        {
            int v = (t < NGRP) ? u.s.hist[t] : 0;
            int tot;
            int ex = bscan256(v, u.s.s5, &tot);
            if (t < NGRP) u.s.cursor[t] = ex;
        }
        __syncthreads();

        if (t < NGRP) {
            size_t idx = ((size_t)dir * NGRP + t) * NCH + c;
            ghist[idx]  = u.s.hist[t];
            gstart[idx] = u.s.cursor[t];
        }
        __syncthreads();

        for (int e = e0 + t; e < e1; e += 256) {
            int k = key[e];
            int pos = atomicAdd(&u.s.cursor[k >> 8], 1);
            u.s.pairs[pos] = ((k & 255) << 16) | pay[e];
        }
        __syncthreads();

        int n = e1 - e0;
        for (int i = t; i < n; i += 256) gchunk[(size_t)c * CHSZ + i] = u.s.pairs[i];
    } else {
        // ---------------- MFMA gemm: xh[128 rows] = X @ W -> fp16 ----------------
        int gb = blockIdx.x - nsort;
        int row0 = gb * 128;

        // stage X tile: f32 -> fp16, XOR-swizzled LDS (byte ^= (row&7)<<4)
        const float4* X4 = (const float4*)X;
        for (int i = t; i < 128 * 32; i += 256) {
            int r = i >> 5, cq = i & 31;           // row, float4-col
            int gr = row0 + r;
            float4 xv = (gr < NN) ? X4[(size_t)gr * 32 + cq]
                                  : make_float4(0.f, 0.f, 0.f, 0.f);
            PK4 pk;
            pk.h[0] = (f16)xv.x; pk.h[1] = (f16)xv.y;
            pk.h[2] = (f16)xv.z; pk.h[3] = (f16)xv.w;
            int byte = (r * 256 + cq * 8) ^ ((r & 7) << 4);
            *(uint2*)((char*)u.g.sXh + byte) = pk.u2;
        }
        __syncthreads();

        int l = t & 63, w = t >> 6;
        int lr = l & 15, lk = l >> 4;              // row/col-in-tile, k-group
        f32x4 acc[2][8];
#pragma unroll
        for (int h = 0; h < 2; ++h)
#pragma unroll
            for (int c = 0; c < 8; ++c) acc[h][c] = (f32x4){0.f, 0.f, 0.f, 0.f};

#pragma unroll
        for (int ks = 0; ks < 4; ++ks) {
            f16x8 afrag[2];
#pragma unroll
            for (int h = 0; h < 2; ++h) {
                int rloc = w * 32 + h * 16 + lr;
                int abyte = (rloc * 256 + ks * 64 + lk * 16) ^ ((rloc & 7) << 4);
                afrag[h] = *(const f16x8*)((const char*)u.g.sXh + abyte);
            }
#pragma unroll
            for (int c = 0; c < 8; ++c) {
                f16x8 bfrag = *(const f16x8*)(Wt + (c * 16 + lr) * 128 + ks * 32 + lk * 8);
                acc[0][c] = __builtin_amdgcn_mfma_f32_16x16x32_f16(afrag[0], bfrag, acc[0][c], 0, 0, 0);
                acc[1][c] = __builtin_amdgcn_mfma_f32_16x16x32_f16(afrag[1], bfrag, acc[1][c], 0, 0, 0);
            }
        }

        // epilogue: C/D col=lane&15, row=(lane>>4)*4+reg
#pragma unroll
        for (int h = 0; h < 2; ++h) {
#pragma unroll
            for (int c = 0; c < 8; ++c) {
                int col = c * 16 + lr;
#pragma unroll
                for (int j = 0; j < 4; ++j) {
                    int row = row0 + w * 32 + h * 16 + lk * 4 + j;
                    if (row < NN) xh[(size_t)row * 128 + col] = (f16)acc[h][c][j];
                }
            }
        }
    }
}

// ---------------- 2a: per-row sum of ghist (1 wave per row) ----------------------
__global__ __launch_bounds__(256) void rowsum_k(const int* __restrict__ ghist,
                                                int* __restrict__ bsum, int NCH) {
    int row = blockIdx.x * 4 + (threadIdx.x >> 6);
    int l = threadIdx.x & 63;
    if (row >= 2 * NGRP) return;
    const int* r = ghist + (size_t)row * NCH;
    int s = 0;
    for (int c = l; c < NCH; c += 64) s += r[c];
#pragma unroll
    for (int k = 32; k >= 1; k >>= 1) s += __shfl_xor(s, k, 64);
    if (l == 0) bsum[row] = s;
}

// ---------------- 2b: scan group sums -> global group starts ---------------------
__global__ __launch_bounds__(256) void bucketbase_k(const int* __restrict__ bsum,
                                                    int* __restrict__ bstart,
                                                    int* __restrict__ off0, int* __restrict__ off1,
                                                    int E) {
    __shared__ int s5[5];
    int dir = blockIdx.x;
    int t = threadIdx.x;
    int v = (t < NGRP) ? bsum[dir * NGRP + t] : 0;
    int tot;
    int ex = bscan256(v, s5, &tot);
    if (t < NGRP) bstart[dir * NGRP + t] = ex;
    if (t == 0) (dir ? off1 : off0)[50000] = E;
}

// ---------------- 3: per-group merge + 256-way fine sort + scatter ---------------
__global__ __launch_bounds__(256) void merge_scatter_k(const int* __restrict__ gchunk0, const int* __restrict__ gchunk1,
                                                       const int* __restrict__ ghist, const int* __restrict__ gstart,
                                                       const int* __restrict__ bstart,
                                                       ushort_t* __restrict__ adj0, ushort_t* __restrict__ adj1,
                                                       int* __restrict__ off0, int* __restrict__ off1,
                                                       int NCH) {
    __shared__ int ssrc[256];
    __shared__ int sdst[257];
    __shared__ int s5[5];
    __shared__ int pairsS[PSZ];
    __shared__ int fcur[256];

    int dir = blockIdx.x / NGRP;
    int g   = blockIdx.x % NGRP;
    int t   = threadIdx.x;
    const int* gchunk   = dir ? gchunk1 : gchunk0;
    ushort_t* adj       = dir ? adj1 : adj0;
    int* offD           = dir ? off1 : off0;

    int len = 0, src = 0;
    if (t < NCH) {
        size_t idx = ((size_t)dir * NGRP + g) * NCH + t;
        len = ghist[idx];
        src = gstart[idx];
    }
    ssrc[t] = src;
    int tot;
    int ex = bscan256(len, s5, &tot);
    sdst[t] = ex;
    if (t == 0) sdst[256] = 0x7FFFFFFF;
    fcur[t] = 0;
    __syncthreads();
    int T = min(tot, PSZ);

    int per = (T + 255) >> 8;
    int i0 = t * per, i1 = min(T, i0 + per);
    if (i0 < i1) {
        int lo = 0, hi = 255;
        while (lo < hi) {
            int mid = (lo + hi + 1) >> 1;
            if (sdst[mid] <= i0) lo = mid; else hi = mid - 1;
        }
        int c = lo;
        for (int i = i0; i < i1; ++i) {
            while (c < 255 && sdst[c + 1] <= i) ++c;
            int p = gchunk[(size_t)c * CHSZ + ssrc[c] + (i - sdst[c])];
            pairsS[i] = p;
            atomicAdd(&fcur[(p >> 16) & 255], 1);
        }
    }
    __syncthreads();

    int cnt = fcur[t];
    __syncthreads();
    int ftot;
    int fex = bscan256(cnt, s5, &ftot);
    int bst = bstart[dir * NGRP + g];
    fcur[t] = fex;
    int d = g * 256 + t;
    if (d < 50000) offD[d] = bst + fex;
    __syncthreads();

    for (int i = t; i < T; i += 256) {
        int p = pairsS[i];
        int slot = atomicAdd(&fcur[(p >> 16) & 255], 1);
        adj[(size_t)bst + slot] = (ushort_t)(p & 0xFFFF);
    }
}

// ---------------- gather-sum core: 1 wave/segment, ushort4 idx, fp16 accum -------
__device__ __forceinline__ void gather_sum(const char* __restrict__ tb,
                                           const ushort_t* __restrict__ adj,
                                           int p0, int p1, int rg, unsigned int cb,
                                           float v[8]) {
    __half2 z = __floats2half2_rn(0.f, 0.f);
    __half2 a0 = z, a1 = z, a2 = z, a3 = z;

    int pre = min((4 - (p0 & 3)) & 3, p1 - p0);
    if (rg < pre) {
        unsigned int o = ((unsigned int)adj[p0 + rg] << 8) + cb;
        HF4 u; u.f4 = *(const float4*)(tb + o);
        a0 = __hadd2(a0, u.h2[0]); a1 = __hadd2(a1, u.h2[1]);
        a2 = __hadd2(a2, u.h2[2]); a3 = __hadd2(a3, u.h2[3]);
    }
    int i = p0 + pre;

    for (; i + 32 <= p1; i += 32) {
        ushort4 q0 = *(const ushort4*)(adj + i + rg * 4);
        ushort4 q1 = *(const ushort4*)(adj + i + 16 + rg * 4);
        HF4 u0, u1, u2, u3, u4, u5, u6, u7;
        u0.f4 = *(const float4*)(tb + (((unsigned int)q0.x << 8) + cb));
        u1.f4 = *(const float4*)(tb + (((unsigned int)q0.y << 8) + cb));
        u2.f4 = *(const float4*)(tb + (((unsigned int)q0.z << 8) + cb));
        u3.f4 = *(const float4*)(tb + (((unsigned int)q0.w << 8) + cb));
        u4.f4 = *(const float4*)(tb + (((unsigned int)q1.x << 8) + cb));
        u5.f4 = *(const float4*)(tb + (((unsigned int)q1.y << 8) + cb));
        u6.f4 = *(const float4*)(tb + (((unsigned int)q1.z << 8) + cb));
        u7.f4 = *(const float4*)(tb + (((unsigned int)q1.w << 8) + cb));
#pragma unroll
        for (int k = 0; k < 4; ++k) {
            __half2 s0 = __hadd2(u0.h2[k], u1.h2[k]);
            __half2 s1 = __hadd2(u2.h2[k], u3.h2[k]);
            __half2 s2 = __hadd2(u4.h2[k], u5.h2[k]);
            __half2 s3 = __hadd2(u6.h2[k], u7.h2[k]);
            __half2 s = __hadd2(__hadd2(s0, s1), __hadd2(s2, s3));
            if (k == 0) a0 = __hadd2(a0, s);
            else if (k == 1) a1 = __hadd2(a1, s);
            else if (k == 2) a2 = __hadd2(a2, s);
            else a3 = __hadd2(a3, s);
        }
    }
    if (i + 16 <= p1) {
        ushort4 q0 = *(const ushort4*)(adj + i + rg * 4);
        HF4 u0, u1, u2, u3;
        u0.f4 = *(const float4*)(tb + (((unsigned int)q0.x << 8) + cb));
        u1.f4 = *(const float4*)(tb + (((unsigned int)q0.y << 8) + cb));
        u2.f4 = *(const float4*)(tb + (((unsigned int)q0.z << 8) + cb));
        u3.f4 = *(const float4*)(tb + (((unsigned int)q0.w << 8) + cb));
#pragma unroll
        for (int k = 0; k < 4; ++k) {
            __half2 s01 = __hadd2(u0.h2[k], u1.h2[k]);
            __half2 s23 = __hadd2(u2.h2[k], u3.h2[k]);
            __half2 s = __hadd2(s01, s23);
            if (k == 0) a0 = __hadd2(a0, s);
            else if (k == 1) a1 = __hadd2(a1, s);
            else if (k == 2) a2 = __hadd2(a2, s);
            else a3 = __hadd2(a3, s);
        }
        i += 16;
    }
    for (; i < p1; i += 4) {
        int r = i + rg;
        if (r < p1) {
            unsigned int o = ((unsigned int)adj[r] << 8) + cb;
            HF4 u; u.f4 = *(const float4*)(tb + o);
            a0 = __hadd2(a0, u.h2[0]); a1 = __hadd2(a1, u.h2[1]);
            a2 = __hadd2(a2, u.h2[2]); a3 = __hadd2(a3, u.h2[3]);
        }
    }

    float2 f0 = __half22float2(a0), f1 = __half22float2(a1);
    float2 f2 = __half22float2(a2), f3 = __half22float2(a3);
    v[0] = f0.x; v[1] = f0.y; v[2] = f1.x; v[3] = f1.y;
    v[4] = f2.x; v[5] = f2.y; v[6] = f3.x; v[7] = f3.y;
#pragma unroll
    for (int k = 0; k < 8; ++k) {
        v[k] += __shfl_xor(v[k], 16, 64);
        v[k] += __shfl_xor(v[k], 32, 64);
    }
}

// ---------------- pass A: m[h] = B_inv[h] * sum_{v in h} x[v] --------------------
__global__ __launch_bounds__(256) void agg_a_k(const char* __restrict__ xb,
                                               const ushort_t* __restrict__ adj,
                                               const int* __restrict__ off,
                                               float4* __restrict__ m4) {
    int t = threadIdx.x;
    int seg = blockIdx.x * 4 + (t >> 6);
    int l = t & 63;
    int rg = l >> 4;
    unsigned int cb = (unsigned int)(l & 15) << 4;
    int p0 = off[seg], p1 = off[seg + 1];
    float v[8];
    gather_sum(xb, adj, p0, p1, rg, cb, v);
    if (l < 16) {
        float inv = (p1 > p0) ? 1.0f / (float)(p1 - p0) : 0.0f;
        HF4 w;
#pragma unroll
        for (int k = 0; k < 4; ++k)
            w.h2[k] = __floats2half2_rn(v[2 * k] * inv, v[2 * k + 1] * inv);
        m4[(size_t)seg * 16 + (l & 15)] = w.f4;
    }
}

// ---------------- pass B: out[v] = softmax(D_inv[v]*sum m[h] + b) (fused) --------
__global__ __launch_bounds__(256) void agg_b_k(const char* __restrict__ mb,
                                               const ushort_t* __restrict__ adj,
                                               const int* __restrict__ off,
                                               const float* __restrict__ bias,
                                               float4* __restrict__ out4) {
    int t = threadIdx.x;
    int seg = blockIdx.x * 4 + (t >> 6);
    int l = t & 63;
    int rg = l >> 4;
    int cc = l & 15;
    unsigned int cb = (unsigned int)cc << 4;
    int p0 = off[seg], p1 = off[seg + 1];
    float v[8];
    gather_sum(mb, adj, p0, p1, rg, cb, v);

    float inv = (p1 > p0) ? 1.0f / (float)(p1 - p0) : 0.0f;
    const float4* b4 = (const float4*)bias;
    float4 bb0 = b4[cc * 2], bb1 = b4[cc * 2 + 1];
    float lg[8];
    lg[0] = v[0] * inv + bb0.x; lg[1] = v[1] * inv + bb0.y;
    lg[2] = v[2] * inv + bb0.z; lg[3] = v[3] * inv + bb0.w;
    lg[4] = v[4] * inv + bb1.x; lg[5] = v[5] * inv + bb1.y;
    lg[6] = v[6] * inv + bb1.z; lg[7] = v[7] * inv + bb1.w;

    float mx = lg[0];
#pragma unroll
    for (int k = 1; k < 8; ++k) mx = fmaxf(mx, lg[k]);
#pragma unroll
    for (int s = 1; s < 16; s <<= 1) mx = fmaxf(mx, __shfl_xor(mx, s, 16));
    float e[8], sm = 0.f;
#pragma unroll
    for (int k = 0; k < 8; ++k) { e[k] = __expf(lg[k] - mx); sm += e[k]; }
#pragma unroll
    for (int s = 1; s < 16; s <<= 1) sm += __shfl_xor(sm, s, 16);
    float r = 1.0f / sm;
    if (l < 16) {
        out4[(size_t)seg * 32 + cc * 2]     = make_float4(e[0] * r, e[1] * r, e[2] * r, e[3] * r);
        out4[(size_t)seg * 32 + cc * 2 + 1] = make_float4(e[4] * r, e[5] * r, e[6] * r, e[7] * r);
    }
}

// ---------------- launcher -------------------------------------------------------
extern "C" void kernel_launch(void* const* d_in, const int* in_sizes, int n_in,
                              void* d_out, int out_size, void* d_ws, size_t ws_size,
                              hipStream_t stream) {
    const float* X  = (const float*)d_in[0];
    const int*   ei = (const int*)d_in[1];
    const float* W  = (const float*)d_in[2];
    const float* b  = (const float*)d_in[3];

    int E = in_sizes[1] / 2;
    const int* nodes  = ei;
    const int* hedges = ei + E;
    int NCH = (E + CHSZ - 1) / CHSZ;       // 196 for E=1.6M (must be <= 256)
    int nsort = 2 * NCH;
    int gemmb = (NN + 127) / 128;          // 391 MFMA-gemm blocks (128 rows each)

    // workspace layout (~50 MB)
    char* p = (char*)d_ws;
    f16* xh = (f16*)p;                    p += (size_t)NN * F * 2;            // 12.8MB
    f16* mh = (f16*)p;                    p += (size_t)NM * F * 2;            // 12.8MB
    ushort_t* adj0 = (ushort_t*)p;        p += (size_t)E * 2;                 // 3.2MB
    ushort_t* adj1 = (ushort_t*)p;        p += (size_t)E * 2;                 // 3.2MB
    int* ghist  = (int*)p;                p += (size_t)2 * NGRP * NCH * 4;    // 300KB
    int* gstart = (int*)p;                p += (size_t)2 * NGRP * NCH * 4;    // 300KB
    int* bstart = (int*)p;                p += (size_t)2 * NGRP * 4;
    int* bsum   = (int*)p;                p += (size_t)2 * NGRP * 4;
    int* off0   = (int*)p;                p += (size_t)(NN + 1) * 4;
    int* off1   = (int*)p;                p += (size_t)(NN + 1) * 4;
    f16* Wt     = (f16*)p;                p += (size_t)128 * 128 * 2;         // 32KB
    p = (char*)(((uintptr_t)p + 15) & ~(uintptr_t)15);
    int* gchunk0 = (int*)p;                                                   // NCH*CHSZ ints
    int* gchunk1 = gchunk0 + (size_t)NCH * CHSZ;

    wprep_k<<<64, 256, 0, stream>>>(W, Wt);
    fat_k<<<nsort + gemmb, 256, 0, stream>>>(X, Wt, xh, nodes, hedges,
                                             gchunk0, gchunk1, ghist, gstart, E, NCH, nsort);
    rowsum_k<<<(2 * NGRP + 3) / 4, 256, 0, stream>>>(ghist, bsum, NCH);
    bucketbase_k<<<2, 256, 0, stream>>>(bsum, bstart, off0, off1, E);
    merge_scatter_k<<<2 * NGRP, 256, 0, stream>>>(gchunk0, gchunk1, ghist, gstart, bstart,
                                                  adj0, adj1, off0, off1, NCH);
    agg_a_k<<<NM / 4, 256, 0, stream>>>((const char*)xh, adj0, off0, (float4*)mh);
    agg_b_k<<<NN / 4, 256, 0, stream>>>((const char*)mh, adj1, off1, b, (float4*)d_out);
}